// Round 5
// baseline (878.868 us; speedup 1.0000x reference)
//
#include <hip/hip_runtime.h>
#include <hip/hip_bf16.h>
#include <cstdint>
#include <cstddef>

#define V_ 8192
#define D_ 1024
#define B_ 32
#define T_ 128
#define NBLK 16

typedef __attribute__((ext_vector_type(8))) short bf16x8;
typedef __attribute__((ext_vector_type(4))) float f32x4;

__device__ __forceinline__ short f2bf(float f) {
  union { float f; unsigned u; } v; v.f = f;
  unsigned r = v.u + 0x7fffu + ((v.u >> 16) & 1u);
  return (short)(r >> 16);
}

__device__ __forceinline__ float bf2f(unsigned short u) {
  union { unsigned u; float f; } c; c.u = ((unsigned)u) << 16;
  return c.f;
}

// tanh(x) = 1 - 2/(exp2(2x*log2e)+1); exact at +/-inf, ~1e-7 abs err
__device__ __forceinline__ float fast_tanh(float x) {
  float t = __builtin_amdgcn_exp2f(x * 2.8853900817779268f);
  return 1.0f - 2.0f * __builtin_amdgcn_rcpf(t + 1.0f);
}

// async global->LDS, 16B per lane. lds base must be wave-uniform.
__device__ __forceinline__ void lds_load16(const void* g, void* l) {
  __builtin_amdgcn_global_load_lds(
      (const __attribute__((address_space(1))) unsigned int*)g,
      (__attribute__((address_space(3))) unsigned int*)l,
      16, 0, 0);
}

// ---------- f32 -> bf16 conversion ----------
__global__ __launch_bounds__(256) void conv_bf16_k(const float* __restrict__ in,
                                                   short* __restrict__ out, int n4) {
  int i = blockIdx.x * 256 + threadIdx.x;  // one float4 per thread
  if (i >= n4) return;
  float4 v = reinterpret_cast<const float4*>(in)[i];
  short4 o;
  o.x = f2bf(v.x); o.y = f2bf(v.y); o.z = f2bf(v.z); o.w = f2bf(v.w);
  reinterpret_cast<short4*>(out)[i] = o;
}

// ---------- W_hh split: Rb = bf16(W_hh, zero diag), Wdiag = diag(W_hh) f32 ----------
__global__ __launch_bounds__(256) void conv_whh(const float* __restrict__ W,
                                                short* __restrict__ Rb,
                                                float* __restrict__ Wdiag) {
  int i = blockIdx.x * 256 + threadIdx.x;   // over D*D = 1048576
  int n = i >> 10;
  int k = i & (D_ - 1);
  float w = W[i];
  Rb[i] = f2bf(k == n ? 0.0f : w);
  if (k == n) Wdiag[n] = w;
}

// ---------- h0 -> Hb slot0 (bf16); zero flags; transpose idx ----------
__global__ __launch_bounds__(256) void init_h(const float* __restrict__ h0,
                                              const int* __restrict__ idx,
                                              short* __restrict__ Hb0,
                                              unsigned* __restrict__ flags,
                                              int* __restrict__ idxT) {
  int i = blockIdx.x * 256 + threadIdx.x;   // over 32768
  Hb0[i] = f2bf(h0[i]);
  if (i < 64) flags[i] = 0u;
  if (i < T_ * B_) {                        // idxT[t][b] = idx[b][t]
    int b = i & (B_ - 1);
    int t = i >> 5;
    idxT[i] = idx[b * T_ + t];
  }
}

// ---------- Wtb[v][d] = bf16(W_ih[d][v] + b_ih[d] + b_hh[d]) ----------
__global__ __launch_bounds__(256) void wtrans(const float* __restrict__ W,
                                              const float* __restrict__ b_ih,
                                              const float* __restrict__ b_hh,
                                              short* __restrict__ Wtb) {
  __shared__ float tile[32][33];
  const int tx = threadIdx.x & 31;
  const int ty = threadIdx.x >> 5;          // 0..7
  const int v0 = blockIdx.x * 32;
  const int d0 = blockIdx.y * 32;
#pragma unroll
  for (int i = 0; i < 32; i += 8)
    tile[ty + i][tx] = W[(size_t)(d0 + ty + i) * V_ + v0 + tx];
  __syncthreads();
  const int d = d0 + tx;
  const float bias = b_ih[d] + b_hh[d];
#pragma unroll
  for (int i = 0; i < 32; i += 8)
    Wtb[(size_t)(v0 + ty + i) * D_ + d] = f2bf(tile[tx][ty + i] + bias);
}

// ---------- persistent recurrence: all 128 steps, 16 blocks x 8 waves ----------
// Cross-block data (Hb slots, flags) moves ONLY via agent-scope relaxed atomics
// (sc0 sc1: bypass L1/L2, coherence point) -> no agent fences, L2 stays warm.
__global__ __launch_bounds__(512) void rnn_all(const short* __restrict__ Rb,
                                               const float* __restrict__ Wdiag,
                                               const float* __restrict__ h0,
                                               const short* __restrict__ Wtb,
                                               const int* __restrict__ idxT,
                                               short* __restrict__ Hb,
                                               unsigned* __restrict__ flags) {
  const int tid = threadIdx.x;
  const int lane = tid & 63;
  const int w = tid >> 6;                  // 0..7, wave-uniform
  const int n0 = blockIdx.x * 64;
  const int fcol = lane & 15;
  const int l16 = lane >> 4;               // 0..3
  const int ks = w * 128;

  __shared__ f32x4 part[8][2][4][64];      // 64 KB
  __shared__ unsigned short hsm[32][64];   // 4 KB

  // persistent B fragments: Rb rows n0..n0+63, this wave's K-slice (64 VGPRs)
  bf16x8 bfrag[4][4];
#pragma unroll
  for (int ni = 0; ni < 4; ++ni) {
    const short* bp = Rb + (size_t)(n0 + ni * 16 + fcol) * D_ + ks + l16 * 8;
#pragma unroll
    for (int kk = 0; kk < 4; ++kk)
      bfrag[ni][kk] = *reinterpret_cast<const bf16x8*>(bp + kk * 32);
  }

  // epilogue role: fixed (m,n) ownership across all steps
  const int mi_e = w >> 2;                 // 0..1
  const int ni_e = w & 3;                  // 0..3
  const int n_e = n0 + ni_e * 16 + fcol;
  const int mbase = mi_e * 16 + l16 * 4;   // +q -> batch row
  const float wd = Wdiag[n_e];
  float hf[4];
#pragma unroll
  for (int q = 0; q < 4; ++q)
    hf[q] = h0[(size_t)(mbase + q) * D_ + n_e];

  // X gather for step 0 (L2-cached loads)
  float xv[4];
  {
    int4 tk = *reinterpret_cast<const int4*>(idxT + mbase);
    xv[0] = bf2f(*(const unsigned short*)(Wtb + (size_t)tk.x * D_ + n_e));
    xv[1] = bf2f(*(const unsigned short*)(Wtb + (size_t)tk.y * D_ + n_e));
    xv[2] = bf2f(*(const unsigned short*)(Wtb + (size_t)tk.z * D_ + n_e));
    xv[3] = bf2f(*(const unsigned short*)(Wtb + (size_t)tk.w * D_ + n_e));
  }

  union U16 { unsigned long long q[2]; bf16x8 v; };

  for (int t = 0; t < T_; ++t) {
    // A fragments from Hb slot t -- agent-scope loads (bypass stale L1/L2)
    const short* hp = Hb + (size_t)t * (B_ * D_);
    bf16x8 af[2][4];
#pragma unroll
    for (int mi = 0; mi < 2; ++mi) {
      const short* ap = hp + (size_t)(mi * 16 + fcol) * D_ + ks + l16 * 8;
#pragma unroll
      for (int kk = 0; kk < 4; ++kk) {
        U16 u;
        u.q[0] = __hip_atomic_load((const unsigned long long*)(ap + kk * 32),
                                   __ATOMIC_RELAXED, __HIP_MEMORY_SCOPE_AGENT);
        u.q[1] = __hip_atomic_load((const unsigned long long*)(ap + kk * 32 + 4),
                                   __ATOMIC_RELAXED, __HIP_MEMORY_SCOPE_AGENT);
        af[mi][kk] = u.v;
      }
    }

#pragma unroll
    for (int mi = 0; mi < 2; ++mi)
#pragma unroll
      for (int ni = 0; ni < 4; ++ni) {
        f32x4 a = {0.f, 0.f, 0.f, 0.f};
#pragma unroll
        for (int kk = 0; kk < 4; ++kk)
          a = __builtin_amdgcn_mfma_f32_16x16x32_bf16(af[mi][kk], bfrag[ni][kk], a, 0, 0, 0);
        part[w][mi][ni][lane] = a;
      }
    __syncthreads();

    // reduce this wave's tile across the 8 K-slices
    f32x4 s = part[0][mi_e][ni_e][lane];
#pragma unroll
    for (int r = 1; r < 8; ++r) s += part[r][mi_e][ni_e][lane];

#pragma unroll
    for (int q = 0; q < 4; ++q) {
      float v = fast_tanh(xv[q] + s[q] + hf[q] * wd);
      hf[q] = v;
      hsm[mbase + q][ni_e * 16 + fcol] = (unsigned short)f2bf(v);
    }

    // prefetch next step's X gather (hides under barrier wait)
    float nxv[4];
    if (t < T_ - 1) {
      int4 tk = *reinterpret_cast<const int4*>(idxT + (t + 1) * B_ + mbase);
      nxv[0] = bf2f(*(const unsigned short*)(Wtb + (size_t)tk.x * D_ + n_e));
      nxv[1] = bf2f(*(const unsigned short*)(Wtb + (size_t)tk.y * D_ + n_e));
      nxv[2] = bf2f(*(const unsigned short*)(Wtb + (size_t)tk.z * D_ + n_e));
      nxv[3] = bf2f(*(const unsigned short*)(Wtb + (size_t)tk.w * D_ + n_e));
    }
    __syncthreads();   // hsm complete (and part reads done)

    // coalesced write-through of h slot t+1: 2 dwords per thread
    short* hn = Hb + (size_t)(t + 1) * (B_ * D_);
#pragma unroll
    for (int rep = 0; rep < 2; ++rep) {
      int c = tid + rep * 512;             // dword id 0..1023
      int m = c >> 5;
      int dc = c & 31;
      unsigned val = *reinterpret_cast<unsigned*>(&hsm[m][dc * 2]);
      __hip_atomic_store((unsigned*)(hn + (size_t)m * D_ + n0 + dc * 2), val,
                         __ATOMIC_RELAXED, __HIP_MEMORY_SCOPE_AGENT);
    }

    if (t < T_ - 1) {
      __syncthreads();  // drains each wave's vmcnt -> stores at coherence point
      if (tid == 0)
        __hip_atomic_store(flags + blockIdx.x, (unsigned)(t + 1),
                           __ATOMIC_RELAXED, __HIP_MEMORY_SCOPE_AGENT);
      if (w == 0) {
        const unsigned gen = (unsigned)(t + 1);
        while (true) {
          unsigned f = gen;
          if (lane < NBLK)
            f = __hip_atomic_load(flags + lane, __ATOMIC_RELAXED,
                                  __HIP_MEMORY_SCOPE_AGENT);
          if (__all((int)(f >= gen))) break;
        }
        __builtin_amdgcn_fence(__ATOMIC_ACQUIRE, "workgroup");  // order only, no L2 inv
      }
      __syncthreads();
#pragma unroll
      for (int q = 0; q < 4; ++q) xv[q] = nxv[q];
    }
  }
}

// ---------- logits GEMM: C[r, v] = sum_d Hb[r,d]*Wb[v,d] + b_o[v] ----------
// M=4096, N=8192, K=1024. bf16 MFMA 16x16x32, tile 128x128, BK=64, 4 waves.
// LDS XOR-swizzle: chunk col ^= (row&7), applied on global SOURCE + ds_read index.
__global__ __launch_bounds__(256) void gemm_logits(const short* __restrict__ A,
                                                   const short* __restrict__ Bt,
                                                   const float* __restrict__ b_o,
                                                   float* __restrict__ C) {
  constexpr int K = D_;
  constexpr int N = V_;
  __shared__ __align__(16) short As[128 * 64];  // 16 KB, [128][8 chunks of 8 bf16]
  __shared__ __align__(16) short Bs[128 * 64];

  const int tid = threadIdx.x;
  const int lane = tid & 63;
  const int w = tid >> 6;
  const int wr = w >> 1, wc = w & 1;
  const int r0 = blockIdx.y * 128;
  const int c0 = blockIdx.x * 128;

  f32x4 acc[4][4] = {};

  for (int k0 = 0; k0 < K; k0 += 64) {
#pragma unroll
    for (int i = 0; i < 4; ++i) {
      int c = tid + 256 * i;                 // per-lane chunk id
      int cb = (tid & ~63) + 256 * i;        // wave-uniform chunk base
      int row = c >> 3;
      int colc = ((c & 7) ^ (row & 7)) * 8;  // pre-swizzled source column
      lds_load16(A + (size_t)(r0 + row) * K + k0 + colc, &As[cb * 8]);
      lds_load16(Bt + (size_t)(c0 + row) * K + k0 + colc, &Bs[cb * 8]);
    }
    asm volatile("s_waitcnt vmcnt(0)" ::: "memory");
    __syncthreads();

#pragma unroll
    for (int kk = 0; kk < 2; ++kk) {
      bf16x8 af[4], bfr[4];
      const int fcol = lane & 15;
      const int chunk = (kk * 4 + (lane >> 4)) ^ (fcol & 7);  // swizzled read chunk
#pragma unroll
      for (int i = 0; i < 4; ++i)
        af[i] = *reinterpret_cast<const bf16x8*>(&As[(wr * 64 + i * 16 + fcol) * 64 + chunk * 8]);
#pragma unroll
      for (int j = 0; j < 4; ++j)
        bfr[j] = *reinterpret_cast<const bf16x8*>(&Bs[(wc * 64 + j * 16 + fcol) * 64 + chunk * 8]);
#pragma unroll
      for (int i = 0; i < 4; ++i)
#pragma unroll
        for (int j = 0; j < 4; ++j)
          acc[i][j] = __builtin_amdgcn_mfma_f32_16x16x32_bf16(af[i], bfr[j], acc[i][j], 0, 0, 0);
    }
    __syncthreads();
  }

  const int fcol = lane & 15;
  const int frow = (lane >> 4) * 4;
#pragma unroll
  for (int i = 0; i < 4; ++i) {
    int row = r0 + wr * 64 + i * 16 + frow;
#pragma unroll
    for (int j = 0; j < 4; ++j) {
      int col = c0 + wc * 64 + j * 16 + fcol;
      float bias = b_o[col];
#pragma unroll
      for (int q = 0; q < 4; ++q)
        C[(size_t)(row + q) * N + col] = acc[i][j][q] + bias;
    }
  }
}

// ---------- in-place log-softmax over rows of 8192 ----------
__global__ __launch_bounds__(256) void logsoftmax(float* __restrict__ out) {
  __shared__ float red[4];
  __shared__ float red2[4];
  float* row = out + (size_t)blockIdx.x * V_;
  const int tid = threadIdx.x;

  float4 v[8];
  float mx = -1e30f;
#pragma unroll
  for (int i = 0; i < 8; ++i) {
    v[i] = *reinterpret_cast<const float4*>(&row[(i * 256 + tid) * 4]);
    mx = fmaxf(mx, fmaxf(fmaxf(v[i].x, v[i].y), fmaxf(v[i].z, v[i].w)));
  }
#pragma unroll
  for (int off = 32; off > 0; off >>= 1) mx = fmaxf(mx, __shfl_xor(mx, off, 64));
  if ((tid & 63) == 0) red[tid >> 6] = mx;
  __syncthreads();
  mx = fmaxf(fmaxf(red[0], red[1]), fmaxf(red[2], red[3]));

  float sum = 0.f;
#pragma unroll
  for (int i = 0; i < 8; ++i)
    sum += expf(v[i].x - mx) + expf(v[i].y - mx) + expf(v[i].z - mx) + expf(v[i].w - mx);
#pragma unroll
  for (int off = 32; off > 0; off >>= 1) sum += __shfl_xor(sum, off, 64);
  if ((tid & 63) == 0) red2[tid >> 6] = sum;
  __syncthreads();
  sum = (red2[0] + red2[1]) + (red2[2] + red2[3]);

  const float lse = mx + logf(sum);
#pragma unroll
  for (int i = 0; i < 8; ++i) {
    float4 o = v[i];
    o.x -= lse; o.y -= lse; o.z -= lse; o.w -= lse;
    *reinterpret_cast<float4*>(&row[(i * 256 + tid) * 4]) = o;
  }
}

extern "C" void kernel_launch(void* const* d_in, const int* in_sizes, int n_in,
                              void* d_out, int out_size, void* d_ws, size_t ws_size,
                              hipStream_t stream) {
  const int* idx = (const int*)d_in[0];
  const float* h0 = (const float*)d_in[1];
  const float* W_ih = (const float*)d_in[2];
  const float* b_ih = (const float*)d_in[3];
  const float* W_hh = (const float*)d_in[4];
  const float* b_hh = (const float*)d_in[5];
  const float* W_ho = (const float*)d_in[6];
  const float* b_o = (const float*)d_in[7];
  float* out = (float*)d_out;

  // workspace layout (~44.2 MB):
  // Hb  bf16 [129][32][1024]   8454144 B @ 0
  // Wb  bf16 [8192][1024]     16777216 B @ 8454144
  // Rb  bf16 [1024][1024]      2097152 B @ 25231360
  // Wdiag f32 [1024]              4096 B @ 27328512
  // Wtb bf16 [8192][1024]     16777216 B @ 27332608
  // flags u32 [64]                4096 B @ 44109824
  // idxT int [128][32]           16384 B @ 44113920
  char* ws = (char*)d_ws;
  short* Hb = (short*)ws;
  short* Wb = (short*)(ws + 8454144);
  short* Rb = (short*)(ws + 25231360);
  float* Wdiag = (float*)(ws + 27328512);
  short* Wtb = (short*)(ws + 27332608);
  unsigned* flags = (unsigned*)(ws + 44109824);
  int* idxT = (int*)(ws + 44113920);

  conv_bf16_k<<<dim3(8192), dim3(256), 0, stream>>>(W_ho, Wb, (V_ * D_) / 4);
  conv_whh<<<dim3(4096), dim3(256), 0, stream>>>(W_hh, Rb, Wdiag);
  init_h<<<dim3(128), dim3(256), 0, stream>>>(h0, idx, Hb, flags, idxT);
  wtrans<<<dim3(V_ / 32, D_ / 32), dim3(256), 0, stream>>>(W_ih, b_ih, b_hh, Wtb);

  rnn_all<<<dim3(NBLK), dim3(512), 0, stream>>>(Rb, Wdiag, h0, Wtb, idxT, Hb, flags);

  // logits for step t read Hb slot t+1  ->  A = Hb + 32768
  gemm_logits<<<dim3(V_ / 128, (T_ * B_) / 128), dim3(256), 0, stream>>>(
      Hb + B_ * D_, Wb, b_o, out);
  logsoftmax<<<dim3(T_ * B_), dim3(256), 0, stream>>>(out);
}

// Round 6
// 869.238 us; speedup vs baseline: 1.0111x; 1.0111x over previous
//
#include <hip/hip_runtime.h>
#include <hip/hip_bf16.h>
#include <cstdint>
#include <cstddef>

#define V_ 8192
#define D_ 1024
#define B_ 32
#define T_ 128
#define NBLK 16

typedef __attribute__((ext_vector_type(8))) short bf16x8;
typedef __attribute__((ext_vector_type(4))) float f32x4;

__device__ __forceinline__ short f2bf(float f) {
  union { float f; unsigned u; } v; v.f = f;
  unsigned r = v.u + 0x7fffu + ((v.u >> 16) & 1u);
  return (short)(r >> 16);
}

__device__ __forceinline__ float bf2f(unsigned short u) {
  union { unsigned u; float f; } c; c.u = ((unsigned)u) << 16;
  return c.f;
}

// tanh(x) = 1 - 2/(exp2(2x*log2e)+1); exact at +/-inf, ~1e-7 abs err
__device__ __forceinline__ float fast_tanh(float x) {
  float t = __builtin_amdgcn_exp2f(x * 2.8853900817779268f);
  return 1.0f - 2.0f * __builtin_amdgcn_rcpf(t + 1.0f);
}

// async global->LDS, 16B per lane. lds base must be wave-uniform.
__device__ __forceinline__ void lds_load16(const void* g, void* l) {
  __builtin_amdgcn_global_load_lds(
      (const __attribute__((address_space(1))) unsigned int*)g,
      (__attribute__((address_space(3))) unsigned int*)l,
      16, 0, 0);
}

// ---------- f32 -> bf16 conversion ----------
__global__ __launch_bounds__(256) void conv_bf16_k(const float* __restrict__ in,
                                                   short* __restrict__ out, int n4) {
  int i = blockIdx.x * 256 + threadIdx.x;  // one float4 per thread
  if (i >= n4) return;
  float4 v = reinterpret_cast<const float4*>(in)[i];
  short4 o;
  o.x = f2bf(v.x); o.y = f2bf(v.y); o.z = f2bf(v.z); o.w = f2bf(v.w);
  reinterpret_cast<short4*>(out)[i] = o;
}

// ---------- W_hh split: Rb = bf16(W_hh, zero diag), Wdiag = diag(W_hh) f32 ----------
__global__ __launch_bounds__(256) void conv_whh(const float* __restrict__ W,
                                                short* __restrict__ Rb,
                                                float* __restrict__ Wdiag) {
  int i = blockIdx.x * 256 + threadIdx.x;   // over D*D = 1048576
  int n = i >> 10;
  int k = i & (D_ - 1);
  float w = W[i];
  Rb[i] = f2bf(k == n ? 0.0f : w);
  if (k == n) Wdiag[n] = w;
}

// ---------- h0 -> Hb slot0 (bf16, via coherence point); flags=0; idxT ----------
__global__ __launch_bounds__(256) void init_h(const float* __restrict__ h0,
                                              const int* __restrict__ idx,
                                              short* __restrict__ Hb0,
                                              unsigned* __restrict__ flags,
                                              int* __restrict__ idxT) {
  int i = blockIdx.x * 256 + threadIdx.x;   // over 16384 (u32 pairs)
  if (i < (B_ * D_) / 2) {
    unsigned lo = (unsigned short)f2bf(h0[2 * i]);
    unsigned hi = (unsigned short)f2bf(h0[2 * i + 1]);
    __hip_atomic_store((unsigned*)Hb0 + i, lo | (hi << 16),
                       __ATOMIC_RELAXED, __HIP_MEMORY_SCOPE_AGENT);
  }
  if (i < 64)
    __hip_atomic_store(flags + i, 0u, __ATOMIC_RELAXED, __HIP_MEMORY_SCOPE_AGENT);
  if (i < T_ * B_) {                        // idxT[t][b] = idx[b][t]
    int b = i & (B_ - 1);
    int t = i >> 5;
    idxT[i] = idx[b * T_ + t];
  }
}

// ---------- Wtb[v][d] = bf16(W_ih[d][v] + b_ih[d] + b_hh[d]) ----------
__global__ __launch_bounds__(256) void wtrans(const float* __restrict__ W,
                                              const float* __restrict__ b_ih,
                                              const float* __restrict__ b_hh,
                                              short* __restrict__ Wtb) {
  __shared__ float tile[32][33];
  const int tx = threadIdx.x & 31;
  const int ty = threadIdx.x >> 5;          // 0..7
  const int v0 = blockIdx.x * 32;
  const int d0 = blockIdx.y * 32;
#pragma unroll
  for (int i = 0; i < 32; i += 8)
    tile[ty + i][tx] = W[(size_t)(d0 + ty + i) * V_ + v0 + tx];
  __syncthreads();
  const int d = d0 + tx;
  const float bias = b_ih[d] + b_hh[d];
#pragma unroll
  for (int i = 0; i < 32; i += 8)
    Wtb[(size_t)(v0 + ty + i) * D_ + d] = f2bf(tile[tx][ty + i] + bias);
}

// ---------- persistent recurrence: dataflow flags, no grid barrier ----------
// 16 blocks x 8 waves. Block b owns n-cols [64b, 64b+64). Wave w: K-slice
// [128w,128w+128) == output tiles of producer blocks 2w, 2w+1. Each wave
// polls ONLY its 2 producer flags, then loads+MFMAs; block-internal LDS
// reduce; epilogue stores h-tile direct to coherence point; tid0 bumps flag.
__global__ __launch_bounds__(512) void rnn_all(const short* __restrict__ Rb,
                                               const float* __restrict__ Wdiag,
                                               const float* __restrict__ h0,
                                               const short* __restrict__ Wtb,
                                               const int* __restrict__ idxT,
                                               short* __restrict__ Hb,
                                               unsigned* __restrict__ flags) {
  const int tid = threadIdx.x;
  const int lane = tid & 63;
  const int w = tid >> 6;                  // 0..7, wave-uniform
  const int n0 = blockIdx.x * 64;
  const int fcol = lane & 15;
  const int l16 = lane >> 4;               // 0..3
  const int ks = w * 128;

  __shared__ f32x4 part[8][2][4][64];      // 64 KB

  // persistent B fragments: Rb rows n0..n0+63, this wave's K-slice
  bf16x8 bfrag[4][4];
#pragma unroll
  for (int ni = 0; ni < 4; ++ni) {
    const short* bp = Rb + (size_t)(n0 + ni * 16 + fcol) * D_ + ks + l16 * 8;
#pragma unroll
    for (int kk = 0; kk < 4; ++kk)
      bfrag[ni][kk] = *reinterpret_cast<const bf16x8*>(bp + kk * 32);
  }

  // epilogue role: fixed (m,n) ownership across all steps
  const int mi_e = w >> 2;                 // 0..1
  const int ni_e = w & 3;                  // 0..3
  const int n_e = n0 + ni_e * 16 + fcol;
  const int mbase = mi_e * 16 + l16 * 4;   // +q -> batch row
  const float wd = Wdiag[n_e];
  float hf[4];
#pragma unroll
  for (int q = 0; q < 4; ++q)
    hf[q] = h0[(size_t)(mbase + q) * D_ + n_e];

  // X gather for step 0 (L2-cached loads)
  float xv[4];
  {
    int4 tk = *reinterpret_cast<const int4*>(idxT + mbase);
    xv[0] = bf2f(*(const unsigned short*)(Wtb + (size_t)tk.x * D_ + n_e));
    xv[1] = bf2f(*(const unsigned short*)(Wtb + (size_t)tk.y * D_ + n_e));
    xv[2] = bf2f(*(const unsigned short*)(Wtb + (size_t)tk.z * D_ + n_e));
    xv[3] = bf2f(*(const unsigned short*)(Wtb + (size_t)tk.w * D_ + n_e));
  }

  union U16 { unsigned long long q[2]; bf16x8 v; };

  for (int t = 0; t < T_; ++t) {
    // (A) wait for this wave's 2 producers (slot t published)
    if (t > 0) {
      const unsigned gen = (unsigned)t;
      while (true) {
        unsigned f = gen;
        if (lane < 2)
          f = __hip_atomic_load(flags + 2 * w + lane, __ATOMIC_RELAXED,
                                __HIP_MEMORY_SCOPE_AGENT);
        if (__all((int)(f >= gen))) break;
      }
    }

    // (B) A fragments from Hb slot t -- coherence-point loads
    const short* hp = Hb + (size_t)t * (B_ * D_);
    bf16x8 af[2][4];
#pragma unroll
    for (int mi = 0; mi < 2; ++mi) {
      const short* ap = hp + (size_t)(mi * 16 + fcol) * D_ + ks + l16 * 8;
#pragma unroll
      for (int kk = 0; kk < 4; ++kk) {
        U16 u;
        u.q[0] = __hip_atomic_load((const unsigned long long*)(ap + kk * 32),
                                   __ATOMIC_RELAXED, __HIP_MEMORY_SCOPE_AGENT);
        u.q[1] = __hip_atomic_load((const unsigned long long*)(ap + kk * 32 + 4),
                                   __ATOMIC_RELAXED, __HIP_MEMORY_SCOPE_AGENT);
        af[mi][kk] = u.v;
      }
    }

    // (C) MFMA partials
#pragma unroll
    for (int mi = 0; mi < 2; ++mi)
#pragma unroll
      for (int ni = 0; ni < 4; ++ni) {
        f32x4 a = {0.f, 0.f, 0.f, 0.f};
#pragma unroll
        for (int kk = 0; kk < 4; ++kk)
          a = __builtin_amdgcn_mfma_f32_16x16x32_bf16(af[mi][kk], bfrag[ni][kk], a, 0, 0, 0);
        part[w][mi][ni][lane] = a;
      }
    __syncthreads();                       // sync1: partials complete

    // (D) reduce across K-slices; tanh; direct store of h slot t+1
    f32x4 s = part[0][mi_e][ni_e][lane];
#pragma unroll
    for (int r = 1; r < 8; ++r) s += part[r][mi_e][ni_e][lane];

    short* hn = Hb + (size_t)(t + 1) * (B_ * D_);
#pragma unroll
    for (int q = 0; q < 4; ++q) {
      float v = fast_tanh(xv[q] + s[q] + hf[q] * wd);
      hf[q] = v;
      __hip_atomic_store((unsigned short*)(hn + (size_t)(mbase + q) * D_ + n_e),
                         (unsigned short)f2bf(v),
                         __ATOMIC_RELAXED, __HIP_MEMORY_SCOPE_AGENT);
    }

    // (E) prefetch next step's X gather (overlaps store drain)
    if (t < T_ - 1) {
      int4 tk = *reinterpret_cast<const int4*>(idxT + (t + 1) * B_ + mbase);
      xv[0] = bf2f(*(const unsigned short*)(Wtb + (size_t)tk.x * D_ + n_e));
      xv[1] = bf2f(*(const unsigned short*)(Wtb + (size_t)tk.y * D_ + n_e));
      xv[2] = bf2f(*(const unsigned short*)(Wtb + (size_t)tk.z * D_ + n_e));
      xv[3] = bf2f(*(const unsigned short*)(Wtb + (size_t)tk.w * D_ + n_e));
    }

    __syncthreads();                       // syncD: all waves' h-stores drained
    if (tid == 0 && t < T_ - 1)
      __hip_atomic_store(flags + blockIdx.x, (unsigned)(t + 1),
                         __ATOMIC_RELAXED, __HIP_MEMORY_SCOPE_AGENT);
    // no barrier here: each wave free-runs into its next poll
  }
}

// ---------- logits GEMM: C[r, v] = sum_d Hb[r,d]*Wb[v,d] + b_o[v] ----------
// M=4096, N=8192, K=1024. bf16 MFMA 16x16x32, tile 128x128, BK=64, 4 waves.
// LDS XOR-swizzle: chunk col ^= (row&7), applied on global SOURCE + ds_read index.
__global__ __launch_bounds__(256) void gemm_logits(const short* __restrict__ A,
                                                   const short* __restrict__ Bt,
                                                   const float* __restrict__ b_o,
                                                   float* __restrict__ C) {
  constexpr int K = D_;
  constexpr int N = V_;
  __shared__ __align__(16) short As[128 * 64];  // 16 KB, [128][8 chunks of 8 bf16]
  __shared__ __align__(16) short Bs[128 * 64];

  const int tid = threadIdx.x;
  const int lane = tid & 63;
  const int w = tid >> 6;
  const int wr = w >> 1, wc = w & 1;
  const int r0 = blockIdx.y * 128;
  const int c0 = blockIdx.x * 128;

  f32x4 acc[4][4] = {};

  for (int k0 = 0; k0 < K; k0 += 64) {
#pragma unroll
    for (int i = 0; i < 4; ++i) {
      int c = tid + 256 * i;                 // per-lane chunk id
      int cb = (tid & ~63) + 256 * i;        // wave-uniform chunk base
      int row = c >> 3;
      int colc = ((c & 7) ^ (row & 7)) * 8;  // pre-swizzled source column
      lds_load16(A + (size_t)(r0 + row) * K + k0 + colc, &As[cb * 8]);
      lds_load16(Bt + (size_t)(c0 + row) * K + k0 + colc, &Bs[cb * 8]);
    }
    asm volatile("s_waitcnt vmcnt(0)" ::: "memory");
    __syncthreads();

#pragma unroll
    for (int kk = 0; kk < 2; ++kk) {
      bf16x8 af[4], bfr[4];
      const int fcol = lane & 15;
      const int chunk = (kk * 4 + (lane >> 4)) ^ (fcol & 7);  // swizzled read chunk
#pragma unroll
      for (int i = 0; i < 4; ++i)
        af[i] = *reinterpret_cast<const bf16x8*>(&As[(wr * 64 + i * 16 + fcol) * 64 + chunk * 8]);
#pragma unroll
      for (int j = 0; j < 4; ++j)
        bfr[j] = *reinterpret_cast<const bf16x8*>(&Bs[(wc * 64 + j * 16 + fcol) * 64 + chunk * 8]);
#pragma unroll
      for (int i = 0; i < 4; ++i)
#pragma unroll
        for (int j = 0; j < 4; ++j)
          acc[i][j] = __builtin_amdgcn_mfma_f32_16x16x32_bf16(af[i], bfr[j], acc[i][j], 0, 0, 0);
    }
    __syncthreads();
  }

  const int fcol = lane & 15;
  const int frow = (lane >> 4) * 4;
#pragma unroll
  for (int i = 0; i < 4; ++i) {
    int row = r0 + wr * 64 + i * 16 + frow;
#pragma unroll
    for (int j = 0; j < 4; ++j) {
      int col = c0 + wc * 64 + j * 16 + fcol;
      float bias = b_o[col];
#pragma unroll
      for (int q = 0; q < 4; ++q)
        C[(size_t)(row + q) * N + col] = acc[i][j][q] + bias;
    }
  }
}

// ---------- in-place log-softmax over rows of 8192 ----------
__global__ __launch_bounds__(256) void logsoftmax(float* __restrict__ out) {
  __shared__ float red[4];
  __shared__ float red2[4];
  float* row = out + (size_t)blockIdx.x * V_;
  const int tid = threadIdx.x;

  float4 v[8];
  float mx = -1e30f;
#pragma unroll
  for (int i = 0; i < 8; ++i) {
    v[i] = *reinterpret_cast<const float4*>(&row[(i * 256 + tid) * 4]);
    mx = fmaxf(mx, fmaxf(fmaxf(v[i].x, v[i].y), fmaxf(v[i].z, v[i].w)));
  }
#pragma unroll
  for (int off = 32; off > 0; off >>= 1) mx = fmaxf(mx, __shfl_xor(mx, off, 64));
  if ((tid & 63) == 0) red[tid >> 6] = mx;
  __syncthreads();
  mx = fmaxf(fmaxf(red[0], red[1]), fmaxf(red[2], red[3]));

  float sum = 0.f;
#pragma unroll
  for (int i = 0; i < 8; ++i)
    sum += expf(v[i].x - mx) + expf(v[i].y - mx) + expf(v[i].z - mx) + expf(v[i].w - mx);
#pragma unroll
  for (int off = 32; off > 0; off >>= 1) sum += __shfl_xor(sum, off, 64);
  if ((tid & 63) == 0) red2[tid >> 6] = sum;
  __syncthreads();
  sum = (red2[0] + red2[1]) + (red2[2] + red2[3]);

  const float lse = mx + logf(sum);
#pragma unroll
  for (int i = 0; i < 8; ++i) {
    float4 o = v[i];
    o.x -= lse; o.y -= lse; o.z -= lse; o.w -= lse;
    *reinterpret_cast<float4*>(&row[(i * 256 + tid) * 4]) = o;
  }
}

extern "C" void kernel_launch(void* const* d_in, const int* in_sizes, int n_in,
                              void* d_out, int out_size, void* d_ws, size_t ws_size,
                              hipStream_t stream) {
  const int* idx = (const int*)d_in[0];
  const float* h0 = (const float*)d_in[1];
  const float* W_ih = (const float*)d_in[2];
  const float* b_ih = (const float*)d_in[3];
  const float* W_hh = (const float*)d_in[4];
  const float* b_hh = (const float*)d_in[5];
  const float* W_ho = (const float*)d_in[6];
  const float* b_o = (const float*)d_in[7];
  float* out = (float*)d_out;

  // workspace layout (~44.2 MB):
  // Hb  bf16 [129][32][1024]   8454144 B @ 0
  // Wb  bf16 [8192][1024]     16777216 B @ 8454144
  // Rb  bf16 [1024][1024]      2097152 B @ 25231360
  // Wdiag f32 [1024]              4096 B @ 27328512
  // Wtb bf16 [8192][1024]     16777216 B @ 27332608
  // flags u32 [64]                4096 B @ 44109824
  // idxT int [128][32]           16384 B @ 44113920
  char* ws = (char*)d_ws;
  short* Hb = (short*)ws;
  short* Wb = (short*)(ws + 8454144);
  short* Rb = (short*)(ws + 25231360);
  float* Wdiag = (float*)(ws + 27328512);
  short* Wtb = (short*)(ws + 27332608);
  unsigned* flags = (unsigned*)(ws + 44109824);
  int* idxT = (int*)(ws + 44113920);

  conv_bf16_k<<<dim3(8192), dim3(256), 0, stream>>>(W_ho, Wb, (V_ * D_) / 4);
  conv_whh<<<dim3(4096), dim3(256), 0, stream>>>(W_hh, Rb, Wdiag);
  init_h<<<dim3(64), dim3(256), 0, stream>>>(h0, idx, Hb, flags, idxT);
  wtrans<<<dim3(V_ / 32, D_ / 32), dim3(256), 0, stream>>>(W_ih, b_ih, b_hh, Wtb);

  rnn_all<<<dim3(NBLK), dim3(512), 0, stream>>>(Rb, Wdiag, h0, Wtb, idxT, Hb, flags);

  // logits for step t read Hb slot t+1  ->  A = Hb + 32768
  gemm_logits<<<dim3(V_ / 128, (T_ * B_) / 128), dim3(256), 0, stream>>>(
      Hb + B_ * D_, Wb, b_o, out);
  logsoftmax<<<dim3(T_ * B_), dim3(256), 0, stream>>>(out);
}

// Round 8
// 837.978 us; speedup vs baseline: 1.0488x; 1.0373x over previous
//
#include <hip/hip_runtime.h>
#include <hip/hip_bf16.h>
#include <cstdint>
#include <cstddef>

#define V_ 8192
#define D_ 1024
#define B_ 32
#define T_ 128
#define NBLK 16
#define SENT 0x7FC0u   // bf16 NaN — impossible tanh output

typedef __attribute__((ext_vector_type(8))) short bf16x8;
typedef __attribute__((ext_vector_type(4))) float f32x4;

__device__ __forceinline__ short f2bf(float f) {
  union { float f; unsigned u; } v; v.f = f;
  unsigned r = v.u + 0x7fffu + ((v.u >> 16) & 1u);
  return (short)(r >> 16);
}

__device__ __forceinline__ float bf2f(unsigned short u) {
  union { unsigned u; float f; } c; c.u = ((unsigned)u) << 16;
  return c.f;
}

// tanh(x) = 1 - 2/(exp2(2x*log2e)+1); exact at +/-inf, ~1e-7 abs err
__device__ __forceinline__ float fast_tanh(float x) {
  float t = __builtin_amdgcn_exp2f(x * 2.8853900817779268f);
  return 1.0f - 2.0f * __builtin_amdgcn_rcpf(t + 1.0f);
}

// async global->LDS, 16B per lane. lds base must be wave-uniform.
__device__ __forceinline__ void lds_load16(const void* g, void* l) {
  __builtin_amdgcn_global_load_lds(
      (const __attribute__((address_space(1))) unsigned int*)g,
      (__attribute__((address_space(3))) unsigned int*)l,
      16, 0, 0);
}

// ---------- f32 -> bf16 conversion ----------
__global__ __launch_bounds__(256) void conv_bf16_k(const float* __restrict__ in,
                                                   short* __restrict__ out, int n4) {
  int i = blockIdx.x * 256 + threadIdx.x;  // one float4 per thread
  if (i >= n4) return;
  float4 v = reinterpret_cast<const float4*>(in)[i];
  short4 o;
  o.x = f2bf(v.x); o.y = f2bf(v.y); o.z = f2bf(v.z); o.w = f2bf(v.w);
  reinterpret_cast<short4*>(out)[i] = o;
}

// ---------- W_hh split: Rb = bf16(W_hh, zero diag), Wdiag = diag(W_hh) f32 ----------
__global__ __launch_bounds__(256) void conv_whh(const float* __restrict__ W,
                                                short* __restrict__ Rb,
                                                float* __restrict__ Wdiag) {
  int i = blockIdx.x * 256 + threadIdx.x;   // over D*D = 1048576
  int n = i >> 10;
  int k = i & (D_ - 1);
  float w = W[i];
  Rb[i] = f2bf(k == n ? 0.0f : w);
  if (k == n) Wdiag[n] = w;
}

// ---------- poison Hb slots 1..128 with bf16-NaN sentinel ----------
__global__ __launch_bounds__(256) void poison_h(int* __restrict__ p, int n4) {
  int i = blockIdx.x * 256 + threadIdx.x;   // int4 chunks
  if (i < n4) {
    int4 v = {(int)0x7FC07FC0, (int)0x7FC07FC0, (int)0x7FC07FC0, (int)0x7FC07FC0};
    reinterpret_cast<int4*>(p)[i] = v;
  }
}

// ---------- h0 -> Hb slot0 (bf16); transpose idx ----------
__global__ __launch_bounds__(256) void init_h(const float* __restrict__ h0,
                                              const int* __restrict__ idx,
                                              short* __restrict__ Hb0,
                                              int* __restrict__ idxT) {
  int i = blockIdx.x * 256 + threadIdx.x;   // over 16384 (u32 pairs)
  if (i < (B_ * D_) / 2) {
    unsigned lo = (unsigned short)f2bf(h0[2 * i]);
    unsigned hi = (unsigned short)f2bf(h0[2 * i + 1]);
    reinterpret_cast<unsigned*>(Hb0)[i] = lo | (hi << 16);
  }
  if (i < T_ * B_) {                        // idxT[t][b] = idx[b][t]
    int b = i & (B_ - 1);
    int t = i >> 5;
    idxT[i] = idx[b * T_ + t];
  }
}

// ---------- Wtb[v][d] = bf16(W_ih[d][v] + b_ih[d] + b_hh[d]) ----------
__global__ __launch_bounds__(256) void wtrans(const float* __restrict__ W,
                                              const float* __restrict__ b_ih,
                                              const float* __restrict__ b_hh,
                                              short* __restrict__ Wtb) {
  __shared__ float tile[32][33];
  const int tx = threadIdx.x & 31;
  const int ty = threadIdx.x >> 5;          // 0..7
  const int v0 = blockIdx.x * 32;
  const int d0 = blockIdx.y * 32;
#pragma unroll
  for (int i = 0; i < 32; i += 8)
    tile[ty + i][tx] = W[(size_t)(d0 + ty + i) * V_ + v0 + tx];
  __syncthreads();
  const int d = d0 + tx;
  const float bias = b_ih[d] + b_hh[d];
#pragma unroll
  for (int i = 0; i < 32; i += 8)
    Wtb[(size_t)(v0 + ty + i) * D_ + d] = f2bf(tile[tx][ty + i] + bias);
}

// ---------- persistent recurrence: sentinel-based pure dataflow ----------
// 16 blocks x 8 waves. Block b owns n-cols [64b, 64b+64). Wave w: K-slice
// [128w,128w+128). Hb slots 1..128 are write-once, pre-poisoned with bf16-NaN;
// consumers poll their own A-fragment data (agent-scope relaxed loads) until
// no sentinel remains. Producers: tanh -> 4 agent u16 stores. No flags, no
// barriers across blocks, minimal coherence round-trips per step.
__global__ __launch_bounds__(512) void rnn_all(const short* __restrict__ Rb,
                                               const float* __restrict__ Wdiag,
                                               const float* __restrict__ h0,
                                               const short* __restrict__ Wtb,
                                               const int* __restrict__ idxT,
                                               short* __restrict__ Hb) {
  const int tid = threadIdx.x;
  const int lane = tid & 63;
  const int w = tid >> 6;                  // 0..7, wave-uniform
  const int n0 = blockIdx.x * 64;
  const int fcol = lane & 15;
  const int l16 = lane >> 4;               // 0..3
  const int ks = w * 128;

  __shared__ f32x4 part[8][2][4][64];      // 64 KB

  // persistent B fragments: Rb rows n0..n0+63, this wave's K-slice
  bf16x8 bfrag[4][4];
#pragma unroll
  for (int ni = 0; ni < 4; ++ni) {
    const short* bp = Rb + (size_t)(n0 + ni * 16 + fcol) * D_ + ks + l16 * 8;
#pragma unroll
    for (int kk = 0; kk < 4; ++kk)
      bfrag[ni][kk] = *reinterpret_cast<const bf16x8*>(bp + kk * 32);
  }

  // epilogue role: fixed (m,n) ownership across all steps
  const int mi_e = w >> 2;                 // 0..1
  const int ni_e = w & 3;                  // 0..3
  const int n_e = n0 + ni_e * 16 + fcol;
  const int mbase = mi_e * 16 + l16 * 4;   // +q -> batch row
  const float wd = Wdiag[n_e];
  float hf[4];
#pragma unroll
  for (int q = 0; q < 4; ++q)
    hf[q] = h0[(size_t)(mbase + q) * D_ + n_e];

  // X gather for step 0 (plain cached loads)
  float xv[4];
  {
    int4 tk = *reinterpret_cast<const int4*>(idxT + mbase);
    xv[0] = bf2f(*(const unsigned short*)(Wtb + (size_t)tk.x * D_ + n_e));
    xv[1] = bf2f(*(const unsigned short*)(Wtb + (size_t)tk.y * D_ + n_e));
    xv[2] = bf2f(*(const unsigned short*)(Wtb + (size_t)tk.z * D_ + n_e));
    xv[3] = bf2f(*(const unsigned short*)(Wtb + (size_t)tk.w * D_ + n_e));
  }

  union U16 { unsigned long long q[2]; bf16x8 v; };

  for (int t = 0; t < T_; ++t) {
    // (A) poll this wave's A-fragment of Hb slot t until sentinel-free
    const short* hp = Hb + (size_t)t * (B_ * D_);
    unsigned long long q[16];
    while (true) {
#pragma unroll
      for (int mi = 0; mi < 2; ++mi) {
        const short* ap = hp + (size_t)(mi * 16 + fcol) * D_ + ks + l16 * 8;
#pragma unroll
        for (int kk = 0; kk < 4; ++kk) {
          q[mi * 8 + kk * 2 + 0] =
              __hip_atomic_load((const unsigned long long*)(ap + kk * 32),
                                __ATOMIC_RELAXED, __HIP_MEMORY_SCOPE_AGENT);
          q[mi * 8 + kk * 2 + 1] =
              __hip_atomic_load((const unsigned long long*)(ap + kk * 32 + 4),
                                __ATOMIC_RELAXED, __HIP_MEMORY_SCOPE_AGENT);
        }
      }
      unsigned bad = 0u;
#pragma unroll
      for (int i = 0; i < 16; ++i) {
        unsigned lo = (unsigned)(q[i] & 0xFFFFFFFFull);
        unsigned hi = (unsigned)(q[i] >> 32);
        bad |= ((lo & 0xFFFFu) == SENT);
        bad |= ((lo >> 16) == SENT);
        bad |= ((hi & 0xFFFFu) == SENT);
        bad |= ((hi >> 16) == SENT);
      }
      if (!__any((int)bad)) break;
    }
    bf16x8 af[2][4];
#pragma unroll
    for (int mi = 0; mi < 2; ++mi)
#pragma unroll
      for (int kk = 0; kk < 4; ++kk) {
        U16 u;
        u.q[0] = q[mi * 8 + kk * 2 + 0];
        u.q[1] = q[mi * 8 + kk * 2 + 1];
        af[mi][kk] = u.v;
      }

    // (B) MFMA partials
#pragma unroll
    for (int mi = 0; mi < 2; ++mi)
#pragma unroll
      for (int ni = 0; ni < 4; ++ni) {
        f32x4 a = {0.f, 0.f, 0.f, 0.f};
#pragma unroll
        for (int kk = 0; kk < 4; ++kk)
          a = __builtin_amdgcn_mfma_f32_16x16x32_bf16(af[mi][kk], bfrag[ni][kk], a, 0, 0, 0);
        part[w][mi][ni][lane] = a;
      }
    __syncthreads();                       // sync1: partials complete

    // (C) reduce across K-slices; tanh; publish h slot t+1 immediately
    f32x4 s = part[0][mi_e][ni_e][lane];
#pragma unroll
    for (int r = 1; r < 8; ++r) s += part[r][mi_e][ni_e][lane];

    short* hn = Hb + (size_t)(t + 1) * (B_ * D_);
#pragma unroll
    for (int q2 = 0; q2 < 4; ++q2) {
      float v = fast_tanh(xv[q2] + s[q2] + hf[q2] * wd);
      hf[q2] = v;
      __hip_atomic_store((unsigned short*)(hn + (size_t)(mbase + q2) * D_ + n_e),
                         (unsigned short)f2bf(v),
                         __ATOMIC_RELAXED, __HIP_MEMORY_SCOPE_AGENT);
    }

    // (D) prefetch next step's X gather (plain cached loads)
    if (t < T_ - 1) {
      int4 tk = *reinterpret_cast<const int4*>(idxT + (t + 1) * B_ + mbase);
      xv[0] = bf2f(*(const unsigned short*)(Wtb + (size_t)tk.x * D_ + n_e));
      xv[1] = bf2f(*(const unsigned short*)(Wtb + (size_t)tk.y * D_ + n_e));
      xv[2] = bf2f(*(const unsigned short*)(Wtb + (size_t)tk.z * D_ + n_e));
      xv[3] = bf2f(*(const unsigned short*)(Wtb + (size_t)tk.w * D_ + n_e));
    }

    __syncthreads();                       // sync2: part[] safe to overwrite
  }
}

// ---------- logits GEMM: C[r, v] = sum_d Hb[r,d]*Wb[v,d] + b_o[v] ----------
// M=4096, N=8192, K=1024. bf16 MFMA 16x16x32, tile 128x128, BK=64, 4 waves.
// LDS XOR-swizzle: chunk col ^= (row&7), applied on global SOURCE + ds_read index.
__global__ __launch_bounds__(256) void gemm_logits(const short* __restrict__ A,
                                                   const short* __restrict__ Bt,
                                                   const float* __restrict__ b_o,
                                                   float* __restrict__ C) {
  constexpr int K = D_;
  constexpr int N = V_;
  __shared__ __align__(16) short As[128 * 64];  // 16 KB, [128][8 chunks of 8 bf16]
  __shared__ __align__(16) short Bs[128 * 64];

  const int tid = threadIdx.x;
  const int lane = tid & 63;
  const int w = tid >> 6;
  const int wr = w >> 1, wc = w & 1;
  const int r0 = blockIdx.y * 128;
  const int c0 = blockIdx.x * 128;

  f32x4 acc[4][4] = {};

  for (int k0 = 0; k0 < K; k0 += 64) {
#pragma unroll
    for (int i = 0; i < 4; ++i) {
      int c = tid + 256 * i;                 // per-lane chunk id
      int cb = (tid & ~63) + 256 * i;        // wave-uniform chunk base
      int row = c >> 3;
      int colc = ((c & 7) ^ (row & 7)) * 8;  // pre-swizzled source column
      lds_load16(A + (size_t)(r0 + row) * K + k0 + colc, &As[cb * 8]);
      lds_load16(Bt + (size_t)(c0 + row) * K + k0 + colc, &Bs[cb * 8]);
    }
    asm volatile("s_waitcnt vmcnt(0)" ::: "memory");
    __syncthreads();

#pragma unroll
    for (int kk = 0; kk < 2; ++kk) {
      bf16x8 af[4], bfr[4];
      const int fcol = lane & 15;
      const int chunk = (kk * 4 + (lane >> 4)) ^ (fcol & 7);  // swizzled read chunk
#pragma unroll
      for (int i = 0; i < 4; ++i)
        af[i] = *reinterpret_cast<const bf16x8*>(&As[(wr * 64 + i * 16 + fcol) * 64 + chunk * 8]);
#pragma unroll
      for (int j = 0; j < 4; ++j)
        bfr[j] = *reinterpret_cast<const bf16x8*>(&Bs[(wc * 64 + j * 16 + fcol) * 64 + chunk * 8]);
#pragma unroll
      for (int i = 0; i < 4; ++i)
#pragma unroll
        for (int j = 0; j < 4; ++j)
          acc[i][j] = __builtin_amdgcn_mfma_f32_16x16x32_bf16(af[i], bfr[j], acc[i][j], 0, 0, 0);
    }
    __syncthreads();
  }

  const int fcol = lane & 15;
  const int frow = (lane >> 4) * 4;
#pragma unroll
  for (int i = 0; i < 4; ++i) {
    int row = r0 + wr * 64 + i * 16 + frow;
#pragma unroll
    for (int j = 0; j < 4; ++j) {
      int col = c0 + wc * 64 + j * 16 + fcol;
      float bias = b_o[col];
#pragma unroll
      for (int q = 0; q < 4; ++q)
        C[(size_t)(row + q) * N + col] = acc[i][j][q] + bias;
    }
  }
}

// ---------- in-place log-softmax over rows of 8192 ----------
__global__ __launch_bounds__(256) void logsoftmax(float* __restrict__ out) {
  __shared__ float red[4];
  __shared__ float red2[4];
  float* row = out + (size_t)blockIdx.x * V_;
  const int tid = threadIdx.x;

  float4 v[8];
  float mx = -1e30f;
#pragma unroll
  for (int i = 0; i < 8; ++i) {
    v[i] = *reinterpret_cast<const float4*>(&row[(i * 256 + tid) * 4]);
    mx = fmaxf(mx, fmaxf(fmaxf(v[i].x, v[i].y), fmaxf(v[i].z, v[i].w)));
  }
#pragma unroll
  for (int off = 32; off > 0; off >>= 1) mx = fmaxf(mx, __shfl_xor(mx, off, 64));
  if ((tid & 63) == 0) red[tid >> 6] = mx;
  __syncthreads();
  mx = fmaxf(fmaxf(red[0], red[1]), fmaxf(red[2], red[3]));

  float sum = 0.f;
#pragma unroll
  for (int i = 0; i < 8; ++i)
    sum += expf(v[i].x - mx) + expf(v[i].y - mx) + expf(v[i].z - mx) + expf(v[i].w - mx);
#pragma unroll
  for (int off = 32; off > 0; off >>= 1) sum += __shfl_xor(sum, off, 64);
  if ((tid & 63) == 0) red2[tid >> 6] = sum;
  __syncthreads();
  sum = (red2[0] + red2[1]) + (red2[2] + red2[3]);

  const float lse = mx + logf(sum);
#pragma unroll
  for (int i = 0; i < 8; ++i) {
    float4 o = v[i];
    o.x -= lse; o.y -= lse; o.z -= lse; o.w -= lse;
    *reinterpret_cast<float4*>(&row[(i * 256 + tid) * 4]) = o;
  }
}

extern "C" void kernel_launch(void* const* d_in, const int* in_sizes, int n_in,
                              void* d_out, int out_size, void* d_ws, size_t ws_size,
                              hipStream_t stream) {
  const int* idx = (const int*)d_in[0];
  const float* h0 = (const float*)d_in[1];
  const float* W_ih = (const float*)d_in[2];
  const float* b_ih = (const float*)d_in[3];
  const float* W_hh = (const float*)d_in[4];
  const float* b_hh = (const float*)d_in[5];
  const float* W_ho = (const float*)d_in[6];
  const float* b_o = (const float*)d_in[7];
  float* out = (float*)d_out;

  // workspace layout (~44.2 MB):
  // Hb  bf16 [129][32][1024]   8454144 B @ 0
  // Wb  bf16 [8192][1024]     16777216 B @ 8454144
  // Rb  bf16 [1024][1024]      2097152 B @ 25231360
  // Wdiag f32 [1024]              4096 B @ 27328512
  // Wtb bf16 [8192][1024]     16777216 B @ 27332608
  // idxT int [128][32]           16384 B @ 44113920
  char* ws = (char*)d_ws;
  short* Hb = (short*)ws;
  short* Wb = (short*)(ws + 8454144);
  short* Rb = (short*)(ws + 25231360);
  float* Wdiag = (float*)(ws + 27328512);
  short* Wtb = (short*)(ws + 27332608);
  int* idxT = (int*)(ws + 44113920);

  conv_bf16_k<<<dim3(8192), dim3(256), 0, stream>>>(W_ho, Wb, (V_ * D_) / 4);
  conv_whh<<<dim3(4096), dim3(256), 0, stream>>>(W_hh, Rb, Wdiag);
  // poison slots 1..128: T_*B_*D_ u16 = 8.39 MB = 524288 int4
  poison_h<<<dim3(2048), dim3(256), 0, stream>>>((int*)(Hb + B_ * D_), (T_ * B_ * D_) / 8);
  init_h<<<dim3(64), dim3(256), 0, stream>>>(h0, idx, Hb, idxT);
  wtrans<<<dim3(V_ / 32, D_ / 32), dim3(256), 0, stream>>>(W_ih, b_ih, b_hh, Wtb);

  rnn_all<<<dim3(NBLK), dim3(512), 0, stream>>>(Rb, Wdiag, h0, Wtb, idxT, Hb);

  // logits for step t read Hb slot t+1  ->  A = Hb + 32768
  gemm_logits<<<dim3(V_ / 128, (T_ * B_) / 128), dim3(256), 0, stream>>>(
      Hb + B_ * D_, Wb, b_o, out);
  logsoftmax<<<dim3(T_ * B_), dim3(256), 0, stream>>>(out);
}